// Round 1
// baseline (642.125 us; speedup 1.0000x reference)
//
#include <hip/hip_runtime.h>

#define FEAT_D 64

// One 64-lane wave per output segment. lane = feature index (D==64 exactly).
// segment_ids is sorted, so the segment's edge range [start,end) is found by
// binary search (lower_bound(s), lower_bound(s+1)). All 64 lanes do the same
// uniform search (broadcast loads, 1 transaction each). Then the wave streams
// the segment's edges: lane d accumulates values[idx[e]*64 + d] (coalesced
// 256 B per edge), finally writes out[s*64 + d] = sum / max(count,1).
__global__ __launch_bounds__(256) void seg_mean_kernel(
    const float* __restrict__ values,
    const int*   __restrict__ gidx,
    const int*   __restrict__ segid,
    float*       __restrict__ out,
    int E, int S)
{
    const int gtid = blockIdx.x * blockDim.x + threadIdx.x;
    const int wave = gtid >> 6;         // one wave per segment
    const int lane = threadIdx.x & 63;  // feature index
    if (wave >= S) return;
    const int s = wave;

    // lower_bound(s): first i with segid[i] >= s
    int lo = 0, hi = E;
    while (lo < hi) {
        int mid = (lo + hi) >> 1;
        if (segid[mid] < s) lo = mid + 1; else hi = mid;
    }
    const int start = lo;

    // lower_bound(s+1): first i with segid[i] > s  (resume from start)
    hi = E;
    while (lo < hi) {
        int mid = (lo + hi) >> 1;
        if (segid[mid] <= s) lo = mid + 1; else hi = mid;
    }
    const int end = lo;

    float sum = 0.0f;
    #pragma unroll 4
    for (int e = start; e < end; ++e) {
        const int idx = gidx[e];                       // broadcast load
        sum += values[(size_t)idx * FEAT_D + lane];    // coalesced 256 B/edge
    }

    const int cnt = end - start;
    const float denom = (float)(cnt > 0 ? cnt : 1);
    out[(size_t)s * FEAT_D + lane] = sum / denom;
}

extern "C" void kernel_launch(void* const* d_in, const int* in_sizes, int n_in,
                              void* d_out, int out_size, void* d_ws, size_t ws_size,
                              hipStream_t stream) {
    const float* values = (const float*)d_in[0];   // [N_SRC, 64] f32
    const int*   gidx   = (const int*)d_in[1];     // [E] (int64 ref -> int32 in harness)
    const int*   segid  = (const int*)d_in[2];     // [E] sorted
    // d_in[3] = num_segments scalar (device); derive S from out_size instead.

    float* out = (float*)d_out;
    const int E = in_sizes[1];
    const int S = out_size / FEAT_D;

    const int threads = 256;                 // 4 waves/block = 4 segments/block
    const int wavesPerBlock = threads / 64;
    const int grid = (S + wavesPerBlock - 1) / wavesPerBlock;

    seg_mean_kernel<<<grid, threads, 0, stream>>>(values, gidx, segid, out, E, S);
}

// Round 2
// 293.389 us; speedup vs baseline: 2.1886x; 2.1886x over previous
//
#include <hip/hip_runtime.h>

#define FEAT_D 64

// Kernel 1: build CSR row pointers from the sorted segment_ids.
// rowptr[s] = lower_bound(segid, s); rowptr[S] = E. Each edge whose segid
// differs from its predecessor writes the whole gap (covers empty segments);
// disjoint ranges -> no races. Edge 0 covers [0, segid[0]]; the last edge
// covers (segid[E-1], S].
__global__ __launch_bounds__(256) void build_rowptr_kernel(
    const int* __restrict__ segid, int* __restrict__ rowptr, int E, int S)
{
    const int e = blockIdx.x * blockDim.x + threadIdx.x;
    if (e >= E) return;
    const int cur  = segid[e];
    const int prev = (e == 0) ? -1 : segid[e - 1];
    for (int s = prev + 1; s <= cur; ++s) rowptr[s] = e;
    if (e == E - 1) {
        for (int s = cur + 1; s <= S; ++s) rowptr[s] = E;
    }
}

// Kernel 2: one 64-lane wave per segment, lane = feature index.
// Edge indices for the whole segment are fetched in ONE coalesced wave load
// and broadcast via __shfl, so the per-edge gathers are independent and can
// all be in flight simultaneously (ILP ~= segment size, avg 16).
__global__ __launch_bounds__(256) void seg_mean_kernel(
    const float* __restrict__ values,
    const int*   __restrict__ gidx,
    const int*   __restrict__ rowptr,
    float*       __restrict__ out,
    int S)
{
    const int wave = (blockIdx.x * blockDim.x + threadIdx.x) >> 6;
    const int lane = threadIdx.x & 63;
    if (wave >= S) return;
    const int s = wave;

    const int start = rowptr[s];
    const int end   = rowptr[s + 1];
    const int cnt   = end - start;

    float sum = 0.0f;
    int myidx = (start + lane < end) ? gidx[start + lane] : 0;
    int base = 0;
    for (;;) {
        const int n = min(64, cnt - base);
        #pragma unroll 4
        for (int e = 0; e < n; ++e) {
            const int idx = __shfl(myidx, e);               // in-register broadcast
            sum += values[(size_t)idx * FEAT_D + lane];     // independent 256 B gather
        }
        base += 64;
        if (base >= cnt) break;                             // common path: cnt <= 64
        myidx = (start + base + lane < end) ? gidx[start + base + lane] : 0;
    }

    const float denom = (float)(cnt > 0 ? cnt : 1);
    out[(size_t)s * FEAT_D + lane] = sum / denom;
}

extern "C" void kernel_launch(void* const* d_in, const int* in_sizes, int n_in,
                              void* d_out, int out_size, void* d_ws, size_t ws_size,
                              hipStream_t stream) {
    const float* values = (const float*)d_in[0];   // [N_SRC, 64] f32
    const int*   gidx   = (const int*)d_in[1];     // [E]
    const int*   segid  = (const int*)d_in[2];     // [E] sorted
    float* out = (float*)d_out;
    int*   rowptr = (int*)d_ws;                    // (S+1) ints of scratch

    const int E = in_sizes[1];
    const int S = out_size / FEAT_D;

    build_rowptr_kernel<<<(E + 255) / 256, 256, 0, stream>>>(segid, rowptr, E, S);

    const int threads = 256;                       // 4 waves = 4 segments / block
    const int grid = (S + 3) / 4;
    seg_mean_kernel<<<grid, threads, 0, stream>>>(values, gidx, rowptr, out, S);
}

// Round 3
// 167.407 us; speedup vs baseline: 3.8357x; 1.7525x over previous
//
#include <hip/hip_runtime.h>

// Kernel 1: CSR row pointers from sorted segment_ids.
// rowptr[s] = lower_bound(segid, s); rowptr[S] = E. Each edge whose segid
// differs from its predecessor writes the whole gap (covers empty segments).
__global__ __launch_bounds__(256) void build_rowptr_kernel(
    const int* __restrict__ segid, int* __restrict__ rowptr, int E, int S)
{
    const int e = blockIdx.x * blockDim.x + threadIdx.x;
    if (e >= E) return;
    const int cur  = segid[e];
    const int prev = (e == 0) ? -1 : segid[e - 1];
    for (int s = prev + 1; s <= cur; ++s) rowptr[s] = e;
    if (e == E - 1) {
        for (int s = cur + 1; s <= S; ++s) rowptr[s] = E;
    }
}

// Kernel 2: one wave per segment, 4 x 16-lane groups.
// Group g (lanes g*16..g*16+15) gathers edge (4*it + g)'s 256 B row as
// 16 x float4 — one wave-level dwordx4 load moves 1 KB covering 4 edges.
// Edge indices are pre-loaded coalesced and broadcast via __shfl.
// Final: butterfly-sum the 4 groups (xor 16, 32), scale by 1/cnt, 16-lane
// float4 store.
__global__ __launch_bounds__(256) void seg_mean_kernel(
    const float4* __restrict__ values4,   // [N_SRC * 16] float4
    const int*    __restrict__ gidx,
    const int*    __restrict__ rowptr,
    float4*       __restrict__ out4,      // [S * 16] float4
    int S)
{
    const int wave = (blockIdx.x * blockDim.x + threadIdx.x) >> 6;
    if (wave >= S) return;
    const int lane = threadIdx.x & 63;
    const int g = lane >> 4;    // edge sub-group 0..3
    const int f = lane & 15;    // float4 slot within the 64-float row

    const int start = rowptr[wave];
    const int end   = rowptr[wave + 1];
    const int cnt   = end - start;

    float sx = 0.f, sy = 0.f, sz = 0.f, sw = 0.f;

    for (int base = 0; base < cnt; base += 64) {
        const int nq = min(64, cnt - base);
        const int p  = start + base + lane;
        int myidx = (p < end) ? gidx[p] : 0;          // coalesced idx pre-load
        const int iters = (nq + 3) >> 2;
        #pragma unroll 4
        for (int it = 0; it < iters; ++it) {
            const int e   = (it << 2) + g;
            const int idx = __shfl(myidx, e);          // in-register broadcast
            if (e < nq) {                              // divergent only in tail
                const float4 v = values4[(size_t)idx * 16 + f];  // 1 KB/wave-instr
                sx += v.x; sy += v.y; sz += v.z; sw += v.w;
            }
        }
    }

    // sum the 4 edge-groups: lanes xor 16 then xor 32
    sx += __shfl_xor(sx, 16); sy += __shfl_xor(sy, 16);
    sz += __shfl_xor(sz, 16); sw += __shfl_xor(sw, 16);
    sx += __shfl_xor(sx, 32); sy += __shfl_xor(sy, 32);
    sz += __shfl_xor(sz, 32); sw += __shfl_xor(sw, 32);

    if (lane < 16) {
        const float inv = 1.0f / (float)(cnt > 0 ? cnt : 1);
        float4 o;
        o.x = sx * inv; o.y = sy * inv; o.z = sz * inv; o.w = sw * inv;
        out4[(size_t)wave * 16 + f] = o;               // 256 B coalesced store
    }
}

extern "C" void kernel_launch(void* const* d_in, const int* in_sizes, int n_in,
                              void* d_out, int out_size, void* d_ws, size_t ws_size,
                              hipStream_t stream) {
    const float4* values4 = (const float4*)d_in[0];  // [N_SRC, 64] f32
    const int*    gidx    = (const int*)d_in[1];     // [E]
    const int*    segid   = (const int*)d_in[2];     // [E] sorted
    float4* out4   = (float4*)d_out;
    int*    rowptr = (int*)d_ws;                     // (S+1) ints of scratch

    const int E = in_sizes[1];
    const int S = out_size / 64;

    build_rowptr_kernel<<<(E + 255) / 256, 256, 0, stream>>>(segid, rowptr, E, S);

    const int threads = 256;                         // 4 waves = 4 segments/block
    const int grid = (S + 3) / 4;
    seg_mean_kernel<<<grid, threads, 0, stream>>>(values4, gidx, rowptr, out4, S);
}